// Round 1
// baseline (100368.597 us; speedup 1.0000x reference)
//
#include <hip/hip_runtime.h>

// RNN_14078902797083: 2-layer tanh RNN + FC + softmax, fp32.
// B=64, T=2048, IN=256, H=512, NCLASS=2.
//
// Strategy: per-layer persistent scan kernels.
//   grid 256 = 32 batch-groups (2 batches each) x 8 hidden-slices (64 outputs each).
//   W_hh (and W_ih) slice rows live in VGPRs (fully unrolled FMA loops).
//   Cross-WG h exchange per step via ws + flags, agent-scope release/acquire.
//   Layer-1 input projection fused into its scan (computed pre-poll, overlaps wait).

#define BB 64
#define TT 2048
#define IN 256
#define HH 512

// workspace layout in floats
#define H1_OFF   0ull                       // [B][T][H] = 67108864 floats (256 MB)
#define HX0_OFF  67108864ull                // [2][B][H] = 65536 floats
#define HX1_OFF  (HX0_OFF + 65536ull)       // [2][B][H]
#define H2L_OFF  (HX1_OFF + 65536ull)       // [B][H] = 32768 floats
#define FLG_OFF  (H2L_OFF + 32768ull)       // 512 ints (flags0: 256, flags1: 256)

// -------------------- layer 0 scan --------------------
// h1_t = tanh(W_ih0 x_t + b + W_hh0 h1_{t-1}); writes full h1[B][T][H].
__global__ __launch_bounds__(256, 1)
void scan_l0(const float* __restrict__ x, const float* __restrict__ Wih,
             const float* __restrict__ Whh, const float* __restrict__ bih,
             const float* __restrict__ bhh, float* __restrict__ h1,
             float* __restrict__ hx, int* __restrict__ flags)
{
    const int bx  = blockIdx.x;
    const int s   = bx >> 5;        // slice 0..7
    const int g   = bx & 31;        // group 0..31
    const int b0  = 2 * g, b1 = 2 * g + 1;
    const int tid = threadIdx.x;
    const int kq  = tid >> 6;       // k-quarter (wave id) 0..3
    const int jl  = tid & 63;       // lane / local output
    const int j   = s * 64 + jl;    // global output row

    __shared__ float red[4][64][2];

    // weights -> VGPRs (one-time)
    float wi[64];
    {
        const float* p = Wih + j * IN + kq * 64;
        #pragma unroll
        for (int i = 0; i < 64; i += 4) {
            float4 v = *(const float4*)(p + i);
            wi[i] = v.x; wi[i+1] = v.y; wi[i+2] = v.z; wi[i+3] = v.w;
        }
    }
    float wh[128];
    {
        const float* p = Whh + j * HH + kq * 128;
        #pragma unroll
        for (int i = 0; i < 128; i += 4) {
            float4 v = *(const float4*)(p + i);
            wh[i] = v.x; wh[i+1] = v.y; wh[i+2] = v.z; wh[i+3] = v.w;
        }
    }
    const float bias = bih[j] + bhh[j];
    int* myflags = flags + g * 8;

    for (int t = 0; t < TT; ++t) {
        float a00=0.f,a01=0.f,a02=0.f,a03=0.f,a10=0.f,a11=0.f,a12=0.f,a13=0.f;
        // input projection (independent of h) — overlaps producer latency
        {
            const float* xp0 = x + ((size_t)b0 * TT + t) * IN + kq * 64;
            const float* xp1 = x + ((size_t)b1 * TT + t) * IN + kq * 64;
            #pragma unroll
            for (int i = 0; i < 64; i += 4) {
                float4 v0 = *(const float4*)(xp0 + i);
                float4 v1 = *(const float4*)(xp1 + i);
                a00 += wi[i]*v0.x; a01 += wi[i+1]*v0.y; a02 += wi[i+2]*v0.z; a03 += wi[i+3]*v0.w;
                a10 += wi[i]*v1.x; a11 += wi[i+1]*v1.y; a12 += wi[i+2]*v1.z; a13 += wi[i+3]*v1.w;
            }
        }
        if (t > 0) {
            // wave-parallel flag poll: lane jl&7 watches flag (jl&7); one load per round
            for (;;) {
                int f = __hip_atomic_load(&myflags[jl & 7], __ATOMIC_RELAXED,
                                          __HIP_MEMORY_SCOPE_AGENT);
                if (__all(f >= t)) break;
            }
            __builtin_amdgcn_fence(__ATOMIC_ACQUIRE, "agent");
            const float* hp  = hx + ((t - 1) & 1) * (BB * HH);
            const float* hp0 = hp + b0 * HH + kq * 128;
            const float* hp1 = hp + b1 * HH + kq * 128;
            #pragma unroll
            for (int i = 0; i < 128; i += 4) {
                float4 v0 = *(const float4*)(hp0 + i);
                float4 v1 = *(const float4*)(hp1 + i);
                a00 += wh[i]*v0.x; a01 += wh[i+1]*v0.y; a02 += wh[i+2]*v0.z; a03 += wh[i+3]*v0.w;
                a10 += wh[i]*v1.x; a11 += wh[i+1]*v1.y; a12 += wh[i+2]*v1.z; a13 += wh[i+3]*v1.w;
            }
        }
        red[kq][jl][0] = (a00 + a01) + (a02 + a03);
        red[kq][jl][1] = (a10 + a11) + (a12 + a13);
        __syncthreads();
        if (tid < 64) {
            float z0 = red[0][jl][0] + red[1][jl][0] + red[2][jl][0] + red[3][jl][0] + bias;
            float z1 = red[0][jl][1] + red[1][jl][1] + red[2][jl][1] + red[3][jl][1] + bias;
            float h0  = tanhf(z0);
            float h1v = tanhf(z1);
            float* hw = hx + (t & 1) * (BB * HH);
            hw[b0 * HH + j] = h0;
            hw[b1 * HH + j] = h1v;
            h1[((size_t)b0 * TT + t) * HH + j] = h0;
            h1[((size_t)b1 * TT + t) * HH + j] = h1v;
            if (jl == 0) {
                // wave-wide vmcnt drain + L2 writeback precede this store (release, agent)
                __hip_atomic_store(&myflags[s], t + 1, __ATOMIC_RELEASE,
                                   __HIP_MEMORY_SCOPE_AGENT);
            }
        }
        // no trailing barrier needed: next-step red writes are gated by the poll
        // (own slice flag only advances after wave0 finishes reading red)
    }
}

// -------------------- layer 1 scan --------------------
// h2_t = tanh(W_ih1 h1_t + b + W_hh1 h2_{t-1}); only final h2 kept.
__global__ __launch_bounds__(256, 1)
void scan_l1(const float* __restrict__ h1, const float* __restrict__ Wih,
             const float* __restrict__ Whh, const float* __restrict__ bih,
             const float* __restrict__ bhh, float* __restrict__ h2l,
             float* __restrict__ hx, int* __restrict__ flags)
{
    const int bx  = blockIdx.x;
    const int s   = bx >> 5;
    const int g   = bx & 31;
    const int b0  = 2 * g, b1 = 2 * g + 1;
    const int tid = threadIdx.x;
    const int kq  = tid >> 6;
    const int jl  = tid & 63;
    const int j   = s * 64 + jl;

    __shared__ float red[4][64][2];
    __shared__ float xsb[2][2 * HH];   // staged h1(t) per parity: [b-sel*512 + k]

    float wi[128];
    {
        const float* p = Wih + j * HH + kq * 128;
        #pragma unroll
        for (int i = 0; i < 128; i += 4) {
            float4 v = *(const float4*)(p + i);
            wi[i] = v.x; wi[i+1] = v.y; wi[i+2] = v.z; wi[i+3] = v.w;
        }
    }
    float wh[128];
    {
        const float* p = Whh + j * HH + kq * 128;
        #pragma unroll
        for (int i = 0; i < 128; i += 4) {
            float4 v = *(const float4*)(p + i);
            wh[i] = v.x; wh[i+1] = v.y; wh[i+2] = v.z; wh[i+3] = v.w;
        }
    }
    const float bias = bih[j] + bhh[j];
    int* myflags = flags + g * 8;

    // prologue: stage h1(t=0) into parity-0 buffer (coalesced float4)
    {
        const int bsel = tid >> 7;
        const int off  = (tid & 127) * 4;
        const int b    = bsel ? b1 : b0;
        float4 v = *(const float4*)&h1[((size_t)b * TT + 0) * HH + off];
        *(float4*)&xsb[0][bsel * HH + off] = v;
    }
    __syncthreads();

    for (int t = 0; t < TT; ++t) {
        float a00=0.f,a01=0.f,a02=0.f,a03=0.f,a10=0.f,a11=0.f,a12=0.f,a13=0.f;
        // fused input projection from LDS-staged h1(t) — before the poll
        {
            const float* q0 = &xsb[t & 1][kq * 128];
            const float* q1 = &xsb[t & 1][HH + kq * 128];
            #pragma unroll
            for (int i = 0; i < 128; i += 4) {
                float4 v0 = *(const float4*)(q0 + i);
                float4 v1 = *(const float4*)(q1 + i);
                a00 += wi[i]*v0.x; a01 += wi[i+1]*v0.y; a02 += wi[i+2]*v0.z; a03 += wi[i+3]*v0.w;
                a10 += wi[i]*v1.x; a11 += wi[i+1]*v1.y; a12 += wi[i+2]*v1.z; a13 += wi[i+3]*v1.w;
            }
        }
        if (t > 0) {
            for (;;) {
                int f = __hip_atomic_load(&myflags[jl & 7], __ATOMIC_RELAXED,
                                          __HIP_MEMORY_SCOPE_AGENT);
                if (__all(f >= t)) break;
            }
            __builtin_amdgcn_fence(__ATOMIC_ACQUIRE, "agent");
            const float* hp  = hx + ((t - 1) & 1) * (BB * HH);
            const float* hp0 = hp + b0 * HH + kq * 128;
            const float* hp1 = hp + b1 * HH + kq * 128;
            #pragma unroll
            for (int i = 0; i < 128; i += 4) {
                float4 v0 = *(const float4*)(hp0 + i);
                float4 v1 = *(const float4*)(hp1 + i);
                a00 += wh[i]*v0.x; a01 += wh[i+1]*v0.y; a02 += wh[i+2]*v0.z; a03 += wh[i+3]*v0.w;
                a10 += wh[i]*v1.x; a11 += wh[i+1]*v1.y; a12 += wh[i+2]*v1.z; a13 += wh[i+3]*v1.w;
            }
        }
        // stage h1(t+1) into the other parity buffer (visible after the barrier)
        if (t + 1 < TT) {
            const int bsel = tid >> 7;
            const int off  = (tid & 127) * 4;
            const int b    = bsel ? b1 : b0;
            float4 v = *(const float4*)&h1[((size_t)b * TT + (t + 1)) * HH + off];
            *(float4*)&xsb[(t + 1) & 1][bsel * HH + off] = v;
        }
        red[kq][jl][0] = (a00 + a01) + (a02 + a03);
        red[kq][jl][1] = (a10 + a11) + (a12 + a13);
        __syncthreads();
        if (tid < 64) {
            float z0 = red[0][jl][0] + red[1][jl][0] + red[2][jl][0] + red[3][jl][0] + bias;
            float z1 = red[0][jl][1] + red[1][jl][1] + red[2][jl][1] + red[3][jl][1] + bias;
            float h0  = tanhf(z0);
            float h1v = tanhf(z1);
            float* hw = hx + (t & 1) * (BB * HH);
            hw[b0 * HH + j] = h0;
            hw[b1 * HH + j] = h1v;
            if (t == TT - 1) {
                h2l[b0 * HH + j] = h0;
                h2l[b1 * HH + j] = h1v;
            }
            if (jl == 0) {
                __hip_atomic_store(&myflags[s], t + 1, __ATOMIC_RELEASE,
                                   __HIP_MEMORY_SCOPE_AGENT);
            }
        }
    }
}

// -------------------- FC + softmax --------------------
__global__ void fc_kernel(const float* __restrict__ h2, const float* __restrict__ w,
                          const float* __restrict__ bvec, float* __restrict__ out)
{
    const int b = threadIdx.x;   // 64 threads
    float z0 = bvec[0], z1 = bvec[1];
    #pragma unroll 4
    for (int k = 0; k < HH; k += 4) {
        float4 h  = *(const float4*)&h2[b * HH + k];
        float4 w0 = *(const float4*)&w[k];
        float4 w1 = *(const float4*)&w[HH + k];
        z0 += h.x*w0.x + h.y*w0.y + h.z*w0.z + h.w*w0.w;
        z1 += h.x*w1.x + h.y*w1.y + h.z*w1.z + h.w*w1.w;
    }
    float m  = fmaxf(z0, z1);
    float e0 = expf(z0 - m), e1 = expf(z1 - m);
    float inv = 1.f / (e0 + e1);
    out[b * 2 + 0] = e0 * inv;
    out[b * 2 + 1] = e1 * inv;
}

extern "C" void kernel_launch(void* const* d_in, const int* in_sizes, int n_in,
                              void* d_out, int out_size, void* d_ws, size_t ws_size,
                              hipStream_t stream)
{
    (void)in_sizes; (void)n_in; (void)out_size; (void)ws_size;
    const float* x    = (const float*)d_in[0];
    const float* Wih0 = (const float*)d_in[1];
    const float* Whh0 = (const float*)d_in[2];
    const float* bih0 = (const float*)d_in[3];
    const float* bhh0 = (const float*)d_in[4];
    const float* Wih1 = (const float*)d_in[5];
    const float* Whh1 = (const float*)d_in[6];
    const float* bih1 = (const float*)d_in[7];
    const float* bhh1 = (const float*)d_in[8];
    const float* fcw  = (const float*)d_in[9];
    const float* fcb  = (const float*)d_in[10];
    float* out = (float*)d_out;

    float* wsf  = (float*)d_ws;
    float* h1   = wsf + H1_OFF;
    float* hx0  = wsf + HX0_OFF;
    float* hx1  = wsf + HX1_OFF;
    float* h2l  = wsf + H2L_OFF;
    int*   flg  = (int*)(wsf + FLG_OFF);
    int*   flg0 = flg;
    int*   flg1 = flg + 256;

    // flags must start at 0 (ws is poisoned 0xAA before every call)
    hipMemsetAsync(flg, 0, 512 * sizeof(int), stream);

    const float* h1c = h1;
    {
        void* args[] = { (void*)&x, (void*)&Wih0, (void*)&Whh0, (void*)&bih0,
                         (void*)&bhh0, (void*)&h1, (void*)&hx0, (void*)&flg0 };
        hipError_t e = hipLaunchCooperativeKernel((const void*)scan_l0, dim3(256),
                                                  dim3(256), args, 0, stream);
        if (e != hipSuccess) {
            scan_l0<<<dim3(256), dim3(256), 0, stream>>>(x, Wih0, Whh0, bih0, bhh0,
                                                         h1, hx0, flg0);
        }
    }
    {
        void* args[] = { (void*)&h1c, (void*)&Wih1, (void*)&Whh1, (void*)&bih1,
                         (void*)&bhh1, (void*)&h2l, (void*)&hx1, (void*)&flg1 };
        hipError_t e = hipLaunchCooperativeKernel((const void*)scan_l1, dim3(256),
                                                  dim3(256), args, 0, stream);
        if (e != hipSuccess) {
            scan_l1<<<dim3(256), dim3(256), 0, stream>>>(h1c, Wih1, Whh1, bih1, bhh1,
                                                         h2l, hx1, flg1);
        }
    }
    fc_kernel<<<dim3(1), dim3(64), 0, stream>>>(h2l, fcw, fcb, out);
}

// Round 2
// 52646.100 us; speedup vs baseline: 1.9065x; 1.9065x over previous
//
#include <hip/hip_runtime.h>

// RNN_14078902797083: 2-layer tanh RNN + FC + softmax, fp32.
// B=64, T=2048, IN=256, H=512, NCLASS=2.
//
// R1 fix: cross-WG exchange via RELAXED agent atomics only (plain sc1 ops,
// no buffer_wbl2 / buffer_inv cache maintenance). Producer ordering via
// explicit s_waitcnt(0) between sc1 data stores and sc1 flag store.
// Consumer h loads staged through LDS with coalesced sc1 loads.

#define BB 64
#define TT 2048
#define IN 256
#define HH 512

// workspace layout in floats
#define H1_OFF   0ull                       // [B][T][H] = 67108864 floats (256 MB)
#define HX0_OFF  67108864ull                // [2][B][H] = 65536 floats
#define HX1_OFF  (HX0_OFF + 65536ull)       // [2][B][H]
#define H2L_OFF  (HX1_OFF + 65536ull)       // [B][H] = 32768 floats
#define FLG_OFF  (H2L_OFF + 32768ull)       // 2 layers x 32 groups x 16 ints (64B-padded)

#define AGENT __HIP_MEMORY_SCOPE_AGENT

__device__ __forceinline__ float ald(const float* p) {
    return __hip_atomic_load(p, __ATOMIC_RELAXED, AGENT);
}
__device__ __forceinline__ void ast(float* p, float v) {
    __hip_atomic_store(p, v, __ATOMIC_RELAXED, AGENT);
}

// -------------------- layer 0 scan --------------------
__global__ __launch_bounds__(256, 1)
void scan_l0(const float* __restrict__ x, const float* __restrict__ Wih,
             const float* __restrict__ Whh, const float* __restrict__ bih,
             const float* __restrict__ bhh, float* __restrict__ h1,
             float* __restrict__ hx, int* __restrict__ flags)
{
    const int bx  = blockIdx.x;
    const int s   = bx >> 5;        // slice 0..7
    const int g   = bx & 31;        // group 0..31
    const int b0  = 2 * g, b1 = 2 * g + 1;
    const int tid = threadIdx.x;
    const int kq  = tid >> 6;       // k-quarter (wave id) 0..3
    const int jl  = tid & 63;       // lane / local output
    const int j   = s * 64 + jl;    // global output row

    __shared__ float red[4][64][2];
    __shared__ float hsh[4][2][128];   // per-wave staged h slice [kq][batch][k]

    float wi[64];
    {
        const float* p = Wih + j * IN + kq * 64;
        #pragma unroll
        for (int i = 0; i < 64; i += 4) {
            float4 v = *(const float4*)(p + i);
            wi[i] = v.x; wi[i+1] = v.y; wi[i+2] = v.z; wi[i+3] = v.w;
        }
    }
    float wh[128];
    {
        const float* p = Whh + j * HH + kq * 128;
        #pragma unroll
        for (int i = 0; i < 128; i += 4) {
            float4 v = *(const float4*)(p + i);
            wh[i] = v.x; wh[i+1] = v.y; wh[i+2] = v.z; wh[i+3] = v.w;
        }
    }
    const float bias = bih[j] + bhh[j];
    int* myflags = flags + g * 16;  // 64B-padded flag line per group

    for (int t = 0; t < TT; ++t) {
        float a00=0.f,a01=0.f,a02=0.f,a03=0.f,a10=0.f,a11=0.f,a12=0.f,a13=0.f;
        // input projection (independent of h) — overlaps producer latency
        {
            const float* xp0 = x + ((size_t)b0 * TT + t) * IN + kq * 64;
            const float* xp1 = x + ((size_t)b1 * TT + t) * IN + kq * 64;
            #pragma unroll
            for (int i = 0; i < 64; i += 4) {
                float4 v0 = *(const float4*)(xp0 + i);
                float4 v1 = *(const float4*)(xp1 + i);
                a00 += wi[i]*v0.x; a01 += wi[i+1]*v0.y; a02 += wi[i+2]*v0.z; a03 += wi[i+3]*v0.w;
                a10 += wi[i]*v1.x; a11 += wi[i+1]*v1.y; a12 += wi[i+2]*v1.z; a13 += wi[i+3]*v1.w;
            }
        }
        if (t > 0) {
            // relaxed agent poll — plain sc1 loads, no cache maintenance
            for (;;) {
                int f = (jl < 8) ? __hip_atomic_load(&myflags[jl], __ATOMIC_RELAXED, AGENT)
                                 : 0x7fffffff;
                if (__all(f >= t)) break;
            }
            // coalesced sc1 stage of this wave's k-quarter into LDS (per-wave, no barrier)
            const float* hp  = hx + ((t - 1) & 1) * (BB * HH);
            const float* hp0 = hp + b0 * HH + kq * 128;
            const float* hp1 = hp + b1 * HH + kq * 128;
            float f0 = ald(hp0 + jl);
            float f1 = ald(hp0 + 64 + jl);
            float f2 = ald(hp1 + jl);
            float f3 = ald(hp1 + 64 + jl);
            hsh[kq][0][jl]      = f0;
            hsh[kq][0][64 + jl] = f1;
            hsh[kq][1][jl]      = f2;
            hsh[kq][1][64 + jl] = f3;
            __builtin_amdgcn_wave_barrier();   // keep ds_writes before ds_reads
            const float* q0 = &hsh[kq][0][0];
            const float* q1 = &hsh[kq][1][0];
            #pragma unroll
            for (int i = 0; i < 128; i += 4) {
                float4 v0 = *(const float4*)(q0 + i);
                float4 v1 = *(const float4*)(q1 + i);
                a00 += wh[i]*v0.x; a01 += wh[i+1]*v0.y; a02 += wh[i+2]*v0.z; a03 += wh[i+3]*v0.w;
                a10 += wh[i]*v1.x; a11 += wh[i+1]*v1.y; a12 += wh[i+2]*v1.z; a13 += wh[i+3]*v1.w;
            }
        }
        red[kq][jl][0] = (a00 + a01) + (a02 + a03);
        red[kq][jl][1] = (a10 + a11) + (a12 + a13);
        __syncthreads();
        if (tid < 64) {
            float z0 = red[0][jl][0] + red[1][jl][0] + red[2][jl][0] + red[3][jl][0] + bias;
            float z1 = red[0][jl][1] + red[1][jl][1] + red[2][jl][1] + red[3][jl][1] + bias;
            float h0  = tanhf(z0);
            float h1v = tanhf(z1);
            float* hw = hx + (t & 1) * (BB * HH);
            ast(hw + b0 * HH + j, h0);          // sc1 stores (no cache maintenance)
            ast(hw + b1 * HH + j, h1v);
            h1[((size_t)b0 * TT + t) * HH + j] = h0;   // plain store (next kernel reads)
            h1[((size_t)b1 * TT + t) * HH + j] = h1v;
            __atomic_signal_fence(__ATOMIC_SEQ_CST);
            __builtin_amdgcn_s_waitcnt(0);      // drain sc1 stores -> globally visible
            __atomic_signal_fence(__ATOMIC_SEQ_CST);
            if (jl == 0) {
                __hip_atomic_store(&myflags[s], t + 1, __ATOMIC_RELAXED, AGENT);
            }
        }
        // no trailing barrier: next-step red writes are gated by the poll
        // (own slice flag only advances after wave0 finishes reading red)
    }
}

// -------------------- layer 1 scan --------------------
__global__ __launch_bounds__(256, 1)
void scan_l1(const float* __restrict__ h1, const float* __restrict__ Wih,
             const float* __restrict__ Whh, const float* __restrict__ bih,
             const float* __restrict__ bhh, float* __restrict__ h2l,
             float* __restrict__ hx, int* __restrict__ flags)
{
    const int bx  = blockIdx.x;
    const int s   = bx >> 5;
    const int g   = bx & 31;
    const int b0  = 2 * g, b1 = 2 * g + 1;
    const int tid = threadIdx.x;
    const int kq  = tid >> 6;
    const int jl  = tid & 63;
    const int j   = s * 64 + jl;

    __shared__ float red[4][64][2];
    __shared__ float hsh[4][2][128];
    __shared__ float xsb[2][2 * HH];   // staged h1(t) per parity: [b-sel*512 + k]

    float wi[128];
    {
        const float* p = Wih + j * HH + kq * 128;
        #pragma unroll
        for (int i = 0; i < 128; i += 4) {
            float4 v = *(const float4*)(p + i);
            wi[i] = v.x; wi[i+1] = v.y; wi[i+2] = v.z; wi[i+3] = v.w;
        }
    }
    float wh[128];
    {
        const float* p = Whh + j * HH + kq * 128;
        #pragma unroll
        for (int i = 0; i < 128; i += 4) {
            float4 v = *(const float4*)(p + i);
            wh[i] = v.x; wh[i+1] = v.y; wh[i+2] = v.z; wh[i+3] = v.w;
        }
    }
    const float bias = bih[j] + bhh[j];
    int* myflags = flags + g * 16;

    // prologue: stage h1(t=0) into parity-0 buffer (coalesced float4, plain loads)
    {
        const int bsel = tid >> 7;
        const int off  = (tid & 127) * 4;
        const int b    = bsel ? b1 : b0;
        float4 v = *(const float4*)&h1[((size_t)b * TT + 0) * HH + off];
        *(float4*)&xsb[0][bsel * HH + off] = v;
    }
    __syncthreads();

    for (int t = 0; t < TT; ++t) {
        float a00=0.f,a01=0.f,a02=0.f,a03=0.f,a10=0.f,a11=0.f,a12=0.f,a13=0.f;
        // fused input projection from LDS-staged h1(t) — before the poll
        {
            const float* q0 = &xsb[t & 1][kq * 128];
            const float* q1 = &xsb[t & 1][HH + kq * 128];
            #pragma unroll
            for (int i = 0; i < 128; i += 4) {
                float4 v0 = *(const float4*)(q0 + i);
                float4 v1 = *(const float4*)(q1 + i);
                a00 += wi[i]*v0.x; a01 += wi[i+1]*v0.y; a02 += wi[i+2]*v0.z; a03 += wi[i+3]*v0.w;
                a10 += wi[i]*v1.x; a11 += wi[i+1]*v1.y; a12 += wi[i+2]*v1.z; a13 += wi[i+3]*v1.w;
            }
        }
        if (t > 0) {
            for (;;) {
                int f = (jl < 8) ? __hip_atomic_load(&myflags[jl], __ATOMIC_RELAXED, AGENT)
                                 : 0x7fffffff;
                if (__all(f >= t)) break;
            }
            const float* hp  = hx + ((t - 1) & 1) * (BB * HH);
            const float* hp0 = hp + b0 * HH + kq * 128;
            const float* hp1 = hp + b1 * HH + kq * 128;
            float f0 = ald(hp0 + jl);
            float f1 = ald(hp0 + 64 + jl);
            float f2 = ald(hp1 + jl);
            float f3 = ald(hp1 + 64 + jl);
            hsh[kq][0][jl]      = f0;
            hsh[kq][0][64 + jl] = f1;
            hsh[kq][1][jl]      = f2;
            hsh[kq][1][64 + jl] = f3;
            __builtin_amdgcn_wave_barrier();
            const float* q0 = &hsh[kq][0][0];
            const float* q1 = &hsh[kq][1][0];
            #pragma unroll
            for (int i = 0; i < 128; i += 4) {
                float4 v0 = *(const float4*)(q0 + i);
                float4 v1 = *(const float4*)(q1 + i);
                a00 += wh[i]*v0.x; a01 += wh[i+1]*v0.y; a02 += wh[i+2]*v0.z; a03 += wh[i+3]*v0.w;
                a10 += wh[i]*v1.x; a11 += wh[i+1]*v1.y; a12 += wh[i+2]*v1.z; a13 += wh[i+3]*v1.w;
            }
        }
        // stage h1(t+1) into the other parity buffer (visible after the barrier)
        if (t + 1 < TT) {
            const int bsel = tid >> 7;
            const int off  = (tid & 127) * 4;
            const int b    = bsel ? b1 : b0;
            float4 v = *(const float4*)&h1[((size_t)b * TT + (t + 1)) * HH + off];
            *(float4*)&xsb[(t + 1) & 1][bsel * HH + off] = v;
        }
        red[kq][jl][0] = (a00 + a01) + (a02 + a03);
        red[kq][jl][1] = (a10 + a11) + (a12 + a13);
        __syncthreads();
        if (tid < 64) {
            float z0 = red[0][jl][0] + red[1][jl][0] + red[2][jl][0] + red[3][jl][0] + bias;
            float z1 = red[0][jl][1] + red[1][jl][1] + red[2][jl][1] + red[3][jl][1] + bias;
            float h0  = tanhf(z0);
            float h1v = tanhf(z1);
            float* hw = hx + (t & 1) * (BB * HH);
            ast(hw + b0 * HH + j, h0);
            ast(hw + b1 * HH + j, h1v);
            if (t == TT - 1) {
                h2l[b0 * HH + j] = h0;
                h2l[b1 * HH + j] = h1v;
            }
            __atomic_signal_fence(__ATOMIC_SEQ_CST);
            __builtin_amdgcn_s_waitcnt(0);
            __atomic_signal_fence(__ATOMIC_SEQ_CST);
            if (jl == 0) {
                __hip_atomic_store(&myflags[s], t + 1, __ATOMIC_RELAXED, AGENT);
            }
        }
    }
}

// -------------------- FC + softmax --------------------
__global__ void fc_kernel(const float* __restrict__ h2, const float* __restrict__ w,
                          const float* __restrict__ bvec, float* __restrict__ out)
{
    const int b = threadIdx.x;   // 64 threads
    float z0 = bvec[0], z1 = bvec[1];
    #pragma unroll 4
    for (int k = 0; k < HH; k += 4) {
        float4 h  = *(const float4*)&h2[b * HH + k];
        float4 w0 = *(const float4*)&w[k];
        float4 w1 = *(const float4*)&w[HH + k];
        z0 += h.x*w0.x + h.y*w0.y + h.z*w0.z + h.w*w0.w;
        z1 += h.x*w1.x + h.y*w1.y + h.z*w1.z + h.w*w1.w;
    }
    float m  = fmaxf(z0, z1);
    float e0 = expf(z0 - m), e1 = expf(z1 - m);
    float inv = 1.f / (e0 + e1);
    out[b * 2 + 0] = e0 * inv;
    out[b * 2 + 1] = e1 * inv;
}

extern "C" void kernel_launch(void* const* d_in, const int* in_sizes, int n_in,
                              void* d_out, int out_size, void* d_ws, size_t ws_size,
                              hipStream_t stream)
{
    (void)in_sizes; (void)n_in; (void)out_size; (void)ws_size;
    const float* x    = (const float*)d_in[0];
    const float* Wih0 = (const float*)d_in[1];
    const float* Whh0 = (const float*)d_in[2];
    const float* bih0 = (const float*)d_in[3];
    const float* bhh0 = (const float*)d_in[4];
    const float* Wih1 = (const float*)d_in[5];
    const float* Whh1 = (const float*)d_in[6];
    const float* bih1 = (const float*)d_in[7];
    const float* bhh1 = (const float*)d_in[8];
    const float* fcw  = (const float*)d_in[9];
    const float* fcb  = (const float*)d_in[10];
    float* out = (float*)d_out;

    float* wsf  = (float*)d_ws;
    float* h1   = wsf + H1_OFF;
    float* hx0  = wsf + HX0_OFF;
    float* hx1  = wsf + HX1_OFF;
    float* h2l  = wsf + H2L_OFF;
    int*   flg  = (int*)(wsf + FLG_OFF);
    int*   flg0 = flg;
    int*   flg1 = flg + 512;

    // flags must start at 0 (ws is poisoned 0xAA before every call)
    hipMemsetAsync(flg, 0, 1024 * sizeof(int), stream);

    const float* h1c = h1;
    {
        void* args[] = { (void*)&x, (void*)&Wih0, (void*)&Whh0, (void*)&bih0,
                         (void*)&bhh0, (void*)&h1, (void*)&hx0, (void*)&flg0 };
        hipError_t e = hipLaunchCooperativeKernel((const void*)scan_l0, dim3(256),
                                                  dim3(256), args, 0, stream);
        if (e != hipSuccess) {
            scan_l0<<<dim3(256), dim3(256), 0, stream>>>(x, Wih0, Whh0, bih0, bhh0,
                                                         h1, hx0, flg0);
        }
    }
    {
        void* args[] = { (void*)&h1c, (void*)&Wih1, (void*)&Whh1, (void*)&bih1,
                         (void*)&bhh1, (void*)&h2l, (void*)&hx1, (void*)&flg1 };
        hipError_t e = hipLaunchCooperativeKernel((const void*)scan_l1, dim3(256),
                                                  dim3(256), args, 0, stream);
        if (e != hipSuccess) {
            scan_l1<<<dim3(256), dim3(256), 0, stream>>>(h1c, Wih1, Whh1, bih1, bhh1,
                                                         h2l, hx1, flg1);
        }
    }
    fc_kernel<<<dim3(1), dim3(64), 0, stream>>>(h2l, fcw, fcb, out);
}

// Round 3
// 47581.345 us; speedup vs baseline: 2.1094x; 1.1064x over previous
//
#include <hip/hip_runtime.h>

// RNN_14078902797083: 2-layer tanh RNN + FC + softmax, fp32.
// B=64, T=2048, IN=256, H=512, NCLASS=2.
//
// R3: tagged-u64 hidden exchange. h values carried as (tag<<32 | float_bits)
// via relaxed agent 8B atomics — data IS the flag: one LLC round trip per
// step, no s_waitcnt drain, no hot flag lines. Each wave polls only the 2
// producer slices it consumes. red[] parity-double-buffered (replaces the
// ordering the old all-flags poll provided). scan_l1 reads h1(t) directly
// from global (broadcast, L1-served) instead of LDS staging.

#define BB 64
#define TT 2048
#define IN 256
#define HH 512

// workspace layout (bytes)
#define H1_OFF   0ull                          // [B][T][H] f32 = 256 MB
#define HX0_OFF  268435456ull                  // [2][B][H] u64 = 512 KB
#define HX1_OFF  (HX0_OFF + 524288ull)         // [2][B][H] u64 = 512 KB
#define H2L_OFF  (HX1_OFF + 524288ull)         // [B][H] f32 = 128 KB

#define AGENT __HIP_MEMORY_SCOPE_AGENT

__device__ __forceinline__ unsigned long long ald64(const unsigned long long* p) {
    return __hip_atomic_load(p, __ATOMIC_RELAXED, AGENT);
}
__device__ __forceinline__ void ast64(unsigned long long* p, unsigned long long v) {
    __hip_atomic_store(p, v, __ATOMIC_RELAXED, AGENT);
}

// -------------------- layer scan (templated on input width) --------------------
// Each WG: slice s (64 output rows), group g (2 batches). 4 waves split k.
// IW = input width (256 for l0, 512 for l1). WRITE_SEQ: store full h sequence.
template <int IW, bool WRITE_SEQ>
__global__ __launch_bounds__(256, 1)
void scan_layer(const float* __restrict__ xin,   // [B][T][IW] input sequence
                const float* __restrict__ Wih,   // [H][IW]
                const float* __restrict__ Whh,   // [H][H]
                const float* __restrict__ bih, const float* __restrict__ bhh,
                float* __restrict__ hseq,        // [B][T][H] (l0) or [B][H] last (l1)
                unsigned long long* __restrict__ hx)  // [2][B][H] tagged
{
    const int bx  = blockIdx.x;
    const int s   = bx >> 5;        // slice 0..7
    const int g   = bx & 31;        // group 0..31
    const int b0  = 2 * g, b1 = 2 * g + 1;
    const int tid = threadIdx.x;
    const int kq  = tid >> 6;       // k-quarter (wave id) 0..3
    const int jl  = tid & 63;       // lane / local output row
    const int j   = s * 64 + jl;    // global output row

    __shared__ float red[2][4][64][2];   // [parity][kq][j][batch]
    __shared__ float hsh[4][2][128];     // per-wave staged h quarter [kq][batch][k]

    const int IQ = IW / 4;               // per-wave input-k chunk
    float wi[IQ];
    {
        const float* p = Wih + j * IW + kq * IQ;
        #pragma unroll
        for (int i = 0; i < IQ; i += 4) {
            float4 v = *(const float4*)(p + i);
            wi[i] = v.x; wi[i+1] = v.y; wi[i+2] = v.z; wi[i+3] = v.w;
        }
    }
    float wh[128];
    {
        const float* p = Whh + j * HH + kq * 128;
        #pragma unroll
        for (int i = 0; i < 128; i += 4) {
            float4 v = *(const float4*)(p + i);
            wh[i] = v.x; wh[i+1] = v.y; wh[i+2] = v.z; wh[i+3] = v.w;
        }
    }
    const float bias = bih[j] + bhh[j];

    for (int t = 0; t < TT; ++t) {
        float a00=0.f,a01=0.f,a02=0.f,a03=0.f,a10=0.f,a11=0.f,a12=0.f,a13=0.f;
        // input projection (independent of h(t-1)) — pre-poll, overlaps producers
        {
            const float* xp0 = xin + ((size_t)b0 * TT + t) * IW + kq * IQ;
            const float* xp1 = xin + ((size_t)b1 * TT + t) * IW + kq * IQ;
            #pragma unroll
            for (int i = 0; i < IQ; i += 4) {
                float4 v0 = *(const float4*)(xp0 + i);
                float4 v1 = *(const float4*)(xp1 + i);
                a00 += wi[i]*v0.x; a01 += wi[i+1]*v0.y; a02 += wi[i+2]*v0.z; a03 += wi[i+3]*v0.w;
                a10 += wi[i]*v1.x; a11 += wi[i+1]*v1.y; a12 += wi[i+2]*v1.z; a13 += wi[i+3]*v1.w;
            }
        }
        if (t > 0) {
            // poll the tagged h data itself (only the 2 slices this wave consumes)
            const unsigned long long* hp = hx + (size_t)((t - 1) & 1) * (BB * HH);
            const unsigned long long* p0 = hp + b0 * HH + kq * 128;
            const unsigned long long* p1 = hp + b1 * HH + kq * 128;
            const unsigned want = (unsigned)t;
            unsigned long long v0, v1, v2, v3;
            for (;;) {
                v0 = ald64(p0 + jl);
                v1 = ald64(p0 + 64 + jl);
                v2 = ald64(p1 + jl);
                v3 = ald64(p1 + 64 + jl);
                bool ok = ((unsigned)(v0 >> 32) == want) &&
                          ((unsigned)(v1 >> 32) == want) &&
                          ((unsigned)(v2 >> 32) == want) &&
                          ((unsigned)(v3 >> 32) == want);
                if (__all(ok)) break;
            }
            hsh[kq][0][jl]      = __uint_as_float((unsigned)v0);
            hsh[kq][0][64 + jl] = __uint_as_float((unsigned)v1);
            hsh[kq][1][jl]      = __uint_as_float((unsigned)v2);
            hsh[kq][1][64 + jl] = __uint_as_float((unsigned)v3);
            __builtin_amdgcn_wave_barrier();   // order ds_writes before ds_reads
            const float* q0 = &hsh[kq][0][0];
            const float* q1 = &hsh[kq][1][0];
            #pragma unroll
            for (int i = 0; i < 128; i += 4) {
                float4 h0 = *(const float4*)(q0 + i);
                float4 h1 = *(const float4*)(q1 + i);
                a00 += wh[i]*h0.x; a01 += wh[i+1]*h0.y; a02 += wh[i+2]*h0.z; a03 += wh[i+3]*h0.w;
                a10 += wh[i]*h1.x; a11 += wh[i+1]*h1.y; a12 += wh[i+2]*h1.z; a13 += wh[i+3]*h1.w;
            }
        }
        red[t & 1][kq][jl][0] = (a00 + a01) + (a02 + a03);
        red[t & 1][kq][jl][1] = (a10 + a11) + (a12 + a13);
        __syncthreads();
        if (tid < 64) {
            const float* r0 = &red[t & 1][0][jl][0];
            float z0 = r0[0] + r0[128] + r0[256] + r0[384] + bias;   // [kq][jl][0]
            float z1 = r0[1] + r0[129] + r0[257] + r0[385] + bias;   // [kq][jl][1]
            float h0  = tanhf(z0);
            float h1v = tanhf(z1);
            unsigned long long* hw = hx + (size_t)(t & 1) * (BB * HH);
            const unsigned long long tagbits = ((unsigned long long)(unsigned)(t + 1)) << 32;
            ast64(hw + b0 * HH + j, tagbits | (unsigned long long)__float_as_uint(h0));
            ast64(hw + b1 * HH + j, tagbits | (unsigned long long)__float_as_uint(h1v));
            if (WRITE_SEQ) {
                hseq[((size_t)b0 * TT + t) * HH + j] = h0;
                hseq[((size_t)b1 * TT + t) * HH + j] = h1v;
            } else if (t == TT - 1) {
                hseq[b0 * HH + j] = h0;
                hseq[b1 * HH + j] = h1v;
            }
        }
        // no trailing barrier: red is parity-double-buffered; hx overwrite skew
        // is bounded by the all-to-all tag dependency within the group.
    }
}

// -------------------- init hx tags (defense vs. stale tags) --------------------
__global__ void zero_hx(unsigned long long* a, unsigned long long* b, int n)
{
    int i = blockIdx.x * blockDim.x + threadIdx.x;
    if (i < n) { a[i] = 0ull; b[i] = 0ull; }
}

// -------------------- FC + softmax --------------------
__global__ void fc_kernel(const float* __restrict__ h2, const float* __restrict__ w,
                          const float* __restrict__ bvec, float* __restrict__ out)
{
    const int b = threadIdx.x;   // 64 threads
    float z0 = bvec[0], z1 = bvec[1];
    #pragma unroll 4
    for (int k = 0; k < HH; k += 4) {
        float4 h  = *(const float4*)&h2[b * HH + k];
        float4 w0 = *(const float4*)&w[k];
        float4 w1 = *(const float4*)&w[HH + k];
        z0 += h.x*w0.x + h.y*w0.y + h.z*w0.z + h.w*w0.w;
        z1 += h.x*w1.x + h.y*w1.y + h.z*w1.z + h.w*w1.w;
    }
    float m  = fmaxf(z0, z1);
    float e0 = expf(z0 - m), e1 = expf(z1 - m);
    float inv = 1.f / (e0 + e1);
    out[b * 2 + 0] = e0 * inv;
    out[b * 2 + 1] = e1 * inv;
}

extern "C" void kernel_launch(void* const* d_in, const int* in_sizes, int n_in,
                              void* d_out, int out_size, void* d_ws, size_t ws_size,
                              hipStream_t stream)
{
    (void)in_sizes; (void)n_in; (void)out_size; (void)ws_size;
    const float* x    = (const float*)d_in[0];
    const float* Wih0 = (const float*)d_in[1];
    const float* Whh0 = (const float*)d_in[2];
    const float* bih0 = (const float*)d_in[3];
    const float* bhh0 = (const float*)d_in[4];
    const float* Wih1 = (const float*)d_in[5];
    const float* Whh1 = (const float*)d_in[6];
    const float* bih1 = (const float*)d_in[7];
    const float* bhh1 = (const float*)d_in[8];
    const float* fcw  = (const float*)d_in[9];
    const float* fcb  = (const float*)d_in[10];
    float* out = (float*)d_out;

    char* ws = (char*)d_ws;
    float* h1  = (float*)(ws + H1_OFF);
    unsigned long long* hx0 = (unsigned long long*)(ws + HX0_OFF);
    unsigned long long* hx1 = (unsigned long long*)(ws + HX1_OFF);
    float* h2l = (float*)(ws + H2L_OFF);

    // clear tags (0 != any wanted tag 1..2048); poison 0xAA would also be fine,
    // but this removes any dependence on the harness's poison pass.
    zero_hx<<<dim3((2 * BB * HH + 255) / 256), dim3(256), 0, stream>>>(hx0, hx1, 2 * BB * HH);

    {
        void* args[] = { (void*)&x, (void*)&Wih0, (void*)&Whh0, (void*)&bih0,
                         (void*)&bhh0, (void*)&h1, (void*)&hx0 };
        hipError_t e = hipLaunchCooperativeKernel((const void*)(scan_layer<IN, true>),
                                                  dim3(256), dim3(256), args, 0, stream);
        if (e != hipSuccess) {
            scan_layer<IN, true><<<dim3(256), dim3(256), 0, stream>>>(
                x, Wih0, Whh0, bih0, bhh0, h1, hx0);
        }
    }
    {
        const float* h1c = h1;
        void* args[] = { (void*)&h1c, (void*)&Wih1, (void*)&Whh1, (void*)&bih1,
                         (void*)&bhh1, (void*)&h2l, (void*)&hx1 };
        hipError_t e = hipLaunchCooperativeKernel((const void*)(scan_layer<HH, false>),
                                                  dim3(256), dim3(256), args, 0, stream);
        if (e != hipSuccess) {
            scan_layer<HH, false><<<dim3(256), dim3(256), 0, stream>>>(
                h1c, Wih1, Whh1, bih1, bhh1, h2l, hx1);
        }
    }
    fc_kernel<<<dim3(1), dim3(64), 0, stream>>>(h2l, fcw, fcb, out);
}

// Round 4
// 47325.281 us; speedup vs baseline: 2.1208x; 1.0054x over previous
//
#include <hip/hip_runtime.h>

// RNN_14078902797083: 2-layer tanh RNN + FC + softmax, fp32.
// B=64, T=2048, IN=256, H=512, NCLASS=2.
//
// R4: fix poll congestion-collapse. R3 spun 4x64-lane uncached loads per
// round (2 KB/wave), saturating the uncached path at ~1.16 TB/s and
// inflating LLC RT to ~1.7us. Now: canary poll (512 B) with s_sleep
// backoff, then one 1.5 KB verified pull. First canary load issued before
// the input-projection FMA block (overlaps one RT with compute).

#define BB 64
#define TT 2048
#define IN 256
#define HH 512

// workspace layout (bytes)
#define H1_OFF   0ull                          // [B][T][H] f32 = 256 MB
#define HX0_OFF  268435456ull                  // [2][B][H] u64 = 512 KB
#define HX1_OFF  (HX0_OFF + 524288ull)         // [2][B][H] u64 = 512 KB
#define H2L_OFF  (HX1_OFF + 524288ull)         // [B][H] f32 = 128 KB

#define AGENT __HIP_MEMORY_SCOPE_AGENT

__device__ __forceinline__ unsigned long long ald64(const unsigned long long* p) {
    return __hip_atomic_load(p, __ATOMIC_RELAXED, AGENT);
}
__device__ __forceinline__ void ast64(unsigned long long* p, unsigned long long v) {
    __hip_atomic_store(p, v, __ATOMIC_RELAXED, AGENT);
}

// -------------------- layer scan (templated on input width) --------------------
// Each WG: slice s (64 output rows), group g (2 batches). 4 waves split k.
template <int IW, bool WRITE_SEQ>
__global__ __launch_bounds__(256, 1)
void scan_layer(const float* __restrict__ xin,   // [B][T][IW]
                const float* __restrict__ Wih,   // [H][IW]
                const float* __restrict__ Whh,   // [H][H]
                const float* __restrict__ bih, const float* __restrict__ bhh,
                float* __restrict__ hseq,        // [B][T][H] (l0) or [B][H] last (l1)
                unsigned long long* __restrict__ hx)  // [2][B][H] tagged
{
    const int bx  = blockIdx.x;
    const int s   = bx >> 5;        // slice 0..7
    const int g   = bx & 31;        // group 0..31
    const int b0  = 2 * g, b1 = 2 * g + 1;
    const int tid = threadIdx.x;
    const int kq  = tid >> 6;       // k-quarter (wave id) 0..3
    const int jl  = tid & 63;       // lane / local output row
    const int j   = s * 64 + jl;    // global output row

    __shared__ float red[2][4][64][2];   // [parity][kq][j][batch]
    __shared__ float hsh[4][2][128];     // per-wave staged h quarter [kq][batch][k]

    const int IQ = IW / 4;
    float wi[IQ];
    {
        const float* p = Wih + j * IW + kq * IQ;
        #pragma unroll
        for (int i = 0; i < IQ; i += 4) {
            float4 v = *(const float4*)(p + i);
            wi[i] = v.x; wi[i+1] = v.y; wi[i+2] = v.z; wi[i+3] = v.w;
        }
    }
    float wh[128];
    {
        const float* p = Whh + j * HH + kq * 128;
        #pragma unroll
        for (int i = 0; i < 128; i += 4) {
            float4 v = *(const float4*)(p + i);
            wh[i] = v.x; wh[i+1] = v.y; wh[i+2] = v.z; wh[i+3] = v.w;
        }
    }
    const float bias = bih[j] + bhh[j];

    for (int t = 0; t < TT; ++t) {
        // pointers for this step's consume (parity (t-1)&1)
        const unsigned long long* hp = hx + (size_t)((t - 1) & 1) * (BB * HH);
        const unsigned long long* p0 = hp + b0 * HH + kq * 128;
        const unsigned long long* p1 = hp + b1 * HH + kq * 128;

        // issue canary load FIRST — its RT overlaps the input projection below
        unsigned long long v0 = (t > 0) ? ald64(p0 + jl) : 0ull;

        float a00=0.f,a01=0.f,a02=0.f,a03=0.f,a10=0.f,a11=0.f,a12=0.f,a13=0.f;
        {
            const float* xp0 = xin + ((size_t)b0 * TT + t) * IW + kq * IQ;
            const float* xp1 = xin + ((size_t)b1 * TT + t) * IW + kq * IQ;
            #pragma unroll
            for (int i = 0; i < IQ; i += 4) {
                float4 vx0 = *(const float4*)(xp0 + i);
                float4 vx1 = *(const float4*)(xp1 + i);
                a00 += wi[i]*vx0.x; a01 += wi[i+1]*vx0.y; a02 += wi[i+2]*vx0.z; a03 += wi[i+3]*vx0.w;
                a10 += wi[i]*vx1.x; a11 += wi[i+1]*vx1.y; a12 += wi[i+2]*vx1.z; a13 += wi[i+3]*vx1.w;
            }
        }
        if (t > 0) {
            const unsigned want = (unsigned)t;
            // canary spin: 512 B/round with backoff
            int r = 0;
            for (;;) {
                if (__all((unsigned)(v0 >> 32) == want)) break;
                if (r < 2) __builtin_amdgcn_s_sleep(1);
                else       __builtin_amdgcn_s_sleep(4);
                ++r;
                v0 = ald64(p0 + jl);
            }
            // remaining three quarters: load + verify (usually 1 round)
            unsigned long long v1, v2, v3;
            for (;;) {
                v1 = ald64(p0 + 64 + jl);
                v2 = ald64(p1 + jl);
                v3 = ald64(p1 + 64 + jl);
                bool ok = ((unsigned)(v1 >> 32) == want) &&
                          ((unsigned)(v2 >> 32) == want) &&
                          ((unsigned)(v3 >> 32) == want);
                if (__all(ok)) break;
                __builtin_amdgcn_s_sleep(1);
            }
            hsh[kq][0][jl]      = __uint_as_float((unsigned)v0);
            hsh[kq][0][64 + jl] = __uint_as_float((unsigned)v1);
            hsh[kq][1][jl]      = __uint_as_float((unsigned)v2);
            hsh[kq][1][64 + jl] = __uint_as_float((unsigned)v3);
            __builtin_amdgcn_wave_barrier();   // order ds_writes before ds_reads
            const float* q0 = &hsh[kq][0][0];
            const float* q1 = &hsh[kq][1][0];
            #pragma unroll
            for (int i = 0; i < 128; i += 4) {
                float4 h0 = *(const float4*)(q0 + i);
                float4 h1 = *(const float4*)(q1 + i);
                a00 += wh[i]*h0.x; a01 += wh[i+1]*h0.y; a02 += wh[i+2]*h0.z; a03 += wh[i+3]*h0.w;
                a10 += wh[i]*h1.x; a11 += wh[i+1]*h1.y; a12 += wh[i+2]*h1.z; a13 += wh[i+3]*h1.w;
            }
        }
        red[t & 1][kq][jl][0] = (a00 + a01) + (a02 + a03);
        red[t & 1][kq][jl][1] = (a10 + a11) + (a12 + a13);
        __syncthreads();
        if (tid < 64) {
            const float* r0 = &red[t & 1][0][jl][0];
            float z0 = r0[0] + r0[128] + r0[256] + r0[384] + bias;
            float z1 = r0[1] + r0[129] + r0[257] + r0[385] + bias;
            float h0  = tanhf(z0);
            float h1v = tanhf(z1);
            unsigned long long* hw = hx + (size_t)(t & 1) * (BB * HH);
            const unsigned long long tagbits = ((unsigned long long)(unsigned)(t + 1)) << 32;
            ast64(hw + b0 * HH + j, tagbits | (unsigned long long)__float_as_uint(h0));
            ast64(hw + b1 * HH + j, tagbits | (unsigned long long)__float_as_uint(h1v));
            if (WRITE_SEQ) {
                hseq[((size_t)b0 * TT + t) * HH + j] = h0;
                hseq[((size_t)b1 * TT + t) * HH + j] = h1v;
            } else if (t == TT - 1) {
                hseq[b0 * HH + j] = h0;
                hseq[b1 * HH + j] = h1v;
            }
        }
        // red is parity-double-buffered; hx overwrite skew is bounded by the
        // all-to-all tag dependency within the group (see R3 analysis).
    }
}

// -------------------- init hx tags --------------------
__global__ void zero_hx(unsigned long long* a, unsigned long long* b, int n)
{
    int i = blockIdx.x * blockDim.x + threadIdx.x;
    if (i < n) { a[i] = 0ull; b[i] = 0ull; }
}

// -------------------- FC + softmax --------------------
__global__ void fc_kernel(const float* __restrict__ h2, const float* __restrict__ w,
                          const float* __restrict__ bvec, float* __restrict__ out)
{
    const int b = threadIdx.x;   // 64 threads
    float z0 = bvec[0], z1 = bvec[1];
    #pragma unroll 4
    for (int k = 0; k < HH; k += 4) {
        float4 h  = *(const float4*)&h2[b * HH + k];
        float4 w0 = *(const float4*)&w[k];
        float4 w1 = *(const float4*)&w[HH + k];
        z0 += h.x*w0.x + h.y*w0.y + h.z*w0.z + h.w*w0.w;
        z1 += h.x*w1.x + h.y*w1.y + h.z*w1.z + h.w*w1.w;
    }
    float m  = fmaxf(z0, z1);
    float e0 = expf(z0 - m), e1 = expf(z1 - m);
    float inv = 1.f / (e0 + e1);
    out[b * 2 + 0] = e0 * inv;
    out[b * 2 + 1] = e1 * inv;
}

extern "C" void kernel_launch(void* const* d_in, const int* in_sizes, int n_in,
                              void* d_out, int out_size, void* d_ws, size_t ws_size,
                              hipStream_t stream)
{
    (void)in_sizes; (void)n_in; (void)out_size; (void)ws_size;
    const float* x    = (const float*)d_in[0];
    const float* Wih0 = (const float*)d_in[1];
    const float* Whh0 = (const float*)d_in[2];
    const float* bih0 = (const float*)d_in[3];
    const float* bhh0 = (const float*)d_in[4];
    const float* Wih1 = (const float*)d_in[5];
    const float* Whh1 = (const float*)d_in[6];
    const float* bih1 = (const float*)d_in[7];
    const float* bhh1 = (const float*)d_in[8];
    const float* fcw  = (const float*)d_in[9];
    const float* fcb  = (const float*)d_in[10];
    float* out = (float*)d_out;

    char* ws = (char*)d_ws;
    float* h1  = (float*)(ws + H1_OFF);
    unsigned long long* hx0 = (unsigned long long*)(ws + HX0_OFF);
    unsigned long long* hx1 = (unsigned long long*)(ws + HX1_OFF);
    float* h2l = (float*)(ws + H2L_OFF);

    zero_hx<<<dim3((2 * BB * HH + 255) / 256), dim3(256), 0, stream>>>(hx0, hx1, 2 * BB * HH);

    {
        void* args[] = { (void*)&x, (void*)&Wih0, (void*)&Whh0, (void*)&bih0,
                         (void*)&bhh0, (void*)&h1, (void*)&hx0 };
        hipError_t e = hipLaunchCooperativeKernel((const void*)(scan_layer<IN, true>),
                                                  dim3(256), dim3(256), args, 0, stream);
        if (e != hipSuccess) {
            scan_layer<IN, true><<<dim3(256), dim3(256), 0, stream>>>(
                x, Wih0, Whh0, bih0, bhh0, h1, hx0);
        }
    }
    {
        const float* h1c = h1;
        void* args[] = { (void*)&h1c, (void*)&Wih1, (void*)&Whh1, (void*)&bih1,
                         (void*)&bhh1, (void*)&h2l, (void*)&hx1 };
        hipError_t e = hipLaunchCooperativeKernel((const void*)(scan_layer<HH, false>),
                                                  dim3(256), dim3(256), args, 0, stream);
        if (e != hipSuccess) {
            scan_layer<HH, false><<<dim3(256), dim3(256), 0, stream>>>(
                h1c, Wih1, Whh1, bih1, bhh1, h2l, hx1);
        }
    }
    fc_kernel<<<dim3(1), dim3(64), 0, stream>>>(h2l, fcw, fcb, out);
}